// Round 7
// baseline (367.958 us; speedup 1.0000x reference)
//
#include <hip/hip_runtime.h>

#define T_TOK 16384
#define IN_F  1024
#define OUT_F 4096
#define NH    32

// ---------------------------------------------------------------------------
// K1: w_t[h][o] = amp[o][h] * cosf(phase[o][h])   (transposed, into workspace)
// ---------------------------------------------------------------------------
__global__ __launch_bounds__(256) void wreal_kernel(
    const float* __restrict__ phase, const float* __restrict__ amp,
    float* __restrict__ w_t)
{
    int idx = blockIdx.x * 256 + threadIdx.x;   // 0 .. 131071
    int o = idx & (OUT_F - 1);
    int h = idx >> 12;                          // idx / 4096
    float p = phase[o * NH + h];
    float a = amp[o * NH + h];
    w_t[h * OUT_F + o] = a * cosf(p);
}

// ---------------------------------------------------------------------------
// K2: res_p[s][h][t] = sum_{i in K-quarter s} x[t][i] * basis[h][i]
// R6-VERBATIM (at its VMEM wall; R5->R6 flat proved occupancy lever exhausted).
// ---------------------------------------------------------------------------
#define G1_TT 64
#define G1_KC 64
#define G1_S  68
#define KSPL  4
#define KQ    (IN_F / KSPL)   // 256

__global__ __launch_bounds__(256, 4) void resonance_kernel(
    const float* __restrict__ x,      // [16384][1024]
    const float* __restrict__ basis,  // [32][1024]
    float* __restrict__ res_p)        // [4][32][16384]
{
    __shared__ float xs[G1_TT * G1_S];   // 17.4 KB
    __shared__ float bs[NH * G1_S];      // 8.7 KB

    const int tid = threadIdx.x;
    const int t0  = blockIdx.x * G1_TT;
    const int ks  = blockIdx.y;              // K-quarter 0..3
    const int kb  = ks * KQ;
    const int ty  = tid >> 4;   // 0..15 : token group (4 tokens)
    const int tx  = tid & 15;   // h = tx, tx+16

    float acc[4][2] = {};

    for (int i0 = kb; i0 < kb + KQ; i0 += G1_KC) {
        #pragma unroll
        for (int it = 0; it < 4; ++it) {
            int lin = it * 256 + tid;
            int r = lin >> 4, c = lin & 15;           // 16 float4 per row
            float4 v = *(const float4*)(x + (size_t)(t0 + r) * IN_F + i0 + 4 * c);
            *(float4*)(xs + r * G1_S + 4 * c) = v;
        }
        #pragma unroll
        for (int it = 0; it < 2; ++it) {
            int lin = it * 256 + tid;
            int r = lin >> 4, c = lin & 15;
            float4 v = *(const float4*)(basis + (size_t)r * IN_F + i0 + 4 * c);
            *(float4*)(bs + r * G1_S + 4 * c) = v;
        }
        __syncthreads();

        #pragma unroll 4
        for (int i = 0; i < G1_KC; i += 4) {
            float4 xa[4], bb[2];
            #pragma unroll
            for (int k = 0; k < 4; ++k)
                xa[k] = *(const float4*)(xs + (4 * ty + k) * G1_S + i);
            #pragma unroll
            for (int j = 0; j < 2; ++j)
                bb[j] = *(const float4*)(bs + (tx + 16 * j) * G1_S + i);
            #pragma unroll
            for (int k = 0; k < 4; ++k) {
                #pragma unroll
                for (int j = 0; j < 2; ++j) {
                    acc[k][j] += xa[k].x * bb[j].x;
                    acc[k][j] += xa[k].y * bb[j].y;
                    acc[k][j] += xa[k].z * bb[j].z;
                    acc[k][j] += xa[k].w * bb[j].w;
                }
            }
        }
        __syncthreads();
    }

    #pragma unroll
    for (int k = 0; k < 4; ++k)
        #pragma unroll
        for (int j = 0; j < 2; ++j)
            res_p[(size_t)(ks * NH + tx + 16 * j) * T_TOK + t0 + 4 * ty + k] = acc[k][j];
}

// ---------------------------------------------------------------------------
// K3: out[t][o] = sum_h (sum_s res_p[s][h][t]) * w_t[h][o]
// Changes vs R6: (1) 2 o-chunks of 128 per block -> rs staged/partial-summed
// once, res_p L2/L3 re-read halved (256->128 MB); (2) grid swapped so t is
// blockIdx.x -> XCD gets a t-slice, res_p working set (~1 MB) L2-resident.
// Inner math, tile shape (64tok x 128out, thread = 4x8), LDS strides, store
// pattern all R6-verbatim. Single wl buffer keeps LDS 25.6 KB -> 6 blocks/CU.
// ---------------------------------------------------------------------------
#define G2_TT 64
#define G2_OT 128
#define G2_OC 2
#define RS_S  68
#define WT_S  132

__global__ __launch_bounds__(256) void holo_out_kernel(
    const float* __restrict__ res_p,  // [4][32][16384]
    const float* __restrict__ w_t,    // [32][4096]
    float* __restrict__ out)          // [16384][4096]
{
    __shared__ float rs[NH * RS_S];   // 8.7 KB
    __shared__ float wl[NH * WT_S];   // 16.9 KB

    const int tid = threadIdx.x;
    const int t0  = blockIdx.x * G2_TT;             // t = fast grid dim (XCD locality)
    const int ob  = blockIdx.y * (G2_OT * G2_OC);   // 256-wide o super-chunk
    const int ty  = tid >> 4;   // 0..15 : token group (4 tokens)
    const int tx  = tid & 15;   // output cols 4*tx and 64+4*tx

    // stage res tile once: 32 rows x 64 floats, summing the 4 K-partials.
    #pragma unroll
    for (int it = 0; it < 2; ++it) {
        int lin = it * 256 + tid;                 // 0..511
        int r = lin >> 4, c = lin & 15;           // 16 float4 per row
        const float* rp = res_p + (size_t)r * T_TOK + t0 + 4 * c;
        float4 v = *(const float4*)(rp);
        #pragma unroll
        for (int s = 1; s < KSPL; ++s) {
            float4 u = *(const float4*)(rp + (size_t)s * NH * T_TOK);
            v.x += u.x; v.y += u.y; v.z += u.z; v.w += u.w;
        }
        *(float4*)(rs + r * RS_S + 4 * c) = v;
    }

    for (int oc = 0; oc < G2_OC; ++oc) {
        const int o0 = ob + oc * G2_OT;

        // stage w_t tile: 32 rows x 128 floats = 1024 float4 -> 4/thread
        #pragma unroll
        for (int it = 0; it < 4; ++it) {
            int lin = it * 256 + tid;
            int r = lin >> 5, c = lin & 31;
            float4 v = *(const float4*)(w_t + (size_t)r * OUT_F + o0 + 4 * c);
            *(float4*)(wl + r * WT_S + 4 * c) = v;
        }
        __syncthreads();   // publishes wl (and rs on first iter)

        float acc[4][8] = {};
        #pragma unroll
        for (int h = 0; h < NH; ++h) {
            float4 rt = *(const float4*)(rs + h * RS_S + 4 * ty);
            float4 wa = *(const float4*)(wl + h * WT_S + 4 * tx);
            float4 wb = *(const float4*)(wl + h * WT_S + 64 + 4 * tx);
            float r4[4] = {rt.x, rt.y, rt.z, rt.w};
            float w8[8] = {wa.x, wa.y, wa.z, wa.w, wb.x, wb.y, wb.z, wb.w};
            #pragma unroll
            for (int k = 0; k < 4; ++k)
                #pragma unroll
                for (int j = 0; j < 8; ++j)
                    acc[k][j] += r4[k] * w8[j];
        }

        __syncthreads();   // all wl reads done (lgkm-only drain; no stores pending)

        #pragma unroll
        for (int k = 0; k < 4; ++k) {
            float* po = out + (size_t)(t0 + 4 * ty + k) * OUT_F + o0;
            *(float4*)(po + 4 * tx)      = make_float4(acc[k][0], acc[k][1], acc[k][2], acc[k][3]);
            *(float4*)(po + 64 + 4 * tx) = make_float4(acc[k][4], acc[k][5], acc[k][6], acc[k][7]);
        }
        // next iter's wl stage overlaps these stores in the memory system
    }
}

// ---------------------------------------------------------------------------
extern "C" void kernel_launch(void* const* d_in, const int* in_sizes, int n_in,
                              void* d_out, int out_size, void* d_ws, size_t ws_size,
                              hipStream_t stream)
{
    const float* x     = (const float*)d_in[0];  // [16384,1024]
    const float* basis = (const float*)d_in[1];  // [32,1024]
    const float* phase = (const float*)d_in[2];  // [4096,32]
    const float* amp   = (const float*)d_in[3];  // [4096,32]
    float* out = (float*)d_out;                  // [16384,4096] fp32

    float* res_p = (float*)d_ws;                        // 4*32*16384 floats = 8 MB
    float* w_t   = res_p + (size_t)KSPL * NH * T_TOK;   // 32*4096 floats = 512 KB

    wreal_kernel<<<dim3((OUT_F * NH) / 256), dim3(256), 0, stream>>>(phase, amp, w_t);
    resonance_kernel<<<dim3(T_TOK / G1_TT, KSPL), dim3(256), 0, stream>>>(x, basis, res_p);
    holo_out_kernel<<<dim3(T_TOK / G2_TT, OUT_F / (G2_OT * G2_OC)), dim3(256), 0, stream>>>(res_p, w_t, out);
}